// Round 5
// baseline (152.331 us; speedup 1.0000x reference)
//
#include <hip/hip_runtime.h>

// Fused UpFIRDn2d via chained MFMA: crop(1) -> +bias -> repeat-up x2 ->
// sep 12-tap FIR -> leaky_relu(0.2)*sqrt(2) -> sep 12-tap FIR -> down x2.
// x: (8,64,130,130) f32; out: (8,64,128,128) f32.
//
// Round 5: all four separable FIR stages are matmuls against small banded
// constant matrices, run on the matrix pipe (bf16 16x16x32 MFMA):
//   B1[r][qq] = sum_c  X[r][c]   * Gt[c][qq]     (W up-conv)   M48 N80 K64
//   U [pp][qq]= sum_r  G2[pp][r] * B1[r][qq]     (H up-conv)   M80 N80 K64
//   leaky*gain elementwise on U (layout-independent)
//   T [a][qq] = sum_pp D[a][pp]  * U[pp][qq]     (H down-conv) M32 N80 K96
//   Out[a][j] = sum_qq T[a][qq]  * D2t[qq][j]    (W down-conv) M32 N32 K96
// Up-grid zero-padding (clip to [0,256)) is folded into 3 edge variants of
// D (top/mid/bot) and D2t (left/mid/right) as zeroed columns/rows.
// A prologue kernel packs all constants into d_ws in fragment order
// (frag = 512 bf16; lane's 8 elems at lane*8) -> coalesced dwordx4 reads.
// C/D layout (col=lane&15, row=quad*4+reg) writes 4 consecutive rows ->
// contiguous b64 stores into transposed-B-operand LDS layouts.
// All K-pad regions explicitly zeroed (avoid 0 x NaN from stale LDS).

#define GAIN_C 1.4142135623730951f
#define NEG_C ((0.2f - 1.0f) * GAIN_C)

typedef short v8s __attribute__((ext_vector_type(8)));
typedef float v4f __attribute__((ext_vector_type(4)));

__device__ __forceinline__ int f2bf(float f) {   // fp32 -> bf16 bits (RNE)
    unsigned u = __float_as_uint(f);
    return (int)((u + 0x7FFFu + ((u >> 16) & 1u)) >> 16) & 0xFFFF;
}

// ---- banded-matrix generators (match the verified round-3/4 index algebra) ----
// band(x, q): up-conv weight linking x-grid index x (local, [0,64)) to
// up-grid index q (local, [0,80)). Even local q -> go[], odd -> ge[].
__device__ float band(int x, int q, const float* fu) {
    if (q >= 74 || x >= 43) return 0.f;
    int p = q >> 1, d = x - p;
    if (q & 1) {
        if (d < 0 || d > 6) return 0.f;
        if (d == 0) return fu[0];
        if (d == 6) return fu[11];
        return fu[2 * d - 1] + fu[2 * d];
    } else {
        if (d < 0 || d > 5) return 0.f;
        return fu[2 * d] + fu[2 * d + 1];
    }
}
// dband(o, q, v): down-conv weight linking out index o to up index q, with
// edge variant v: 0 = first tile (zero q<5), 2 = last tile (zero q>=69).
__device__ float dband(int o, int q, int v, const float* fd) {
    if (q >= 74) return 0.f;
    if (v == 0 && q < 5) return 0.f;
    if (v == 2 && q >= 69) return 0.f;
    int k = q - 2 * o;
    if (k < 0 || k > 11) return 0.f;
    return fd[k];
}

// d_ws layout (bf16 elems): GtB [0,5120) | G2A [5120,10240) |
// DA 3 variants [10240,19456) | D2B 3 variants [19456,28672)
__global__ __launch_bounds__(256) void build_consts(
    const float* __restrict__ fu, const float* __restrict__ fd,
    short* __restrict__ ws)
{
    int idx = blockIdx.x * 256 + threadIdx.x;   // grid covers 28672 exactly
    int rel, fi, l, j;
    float val;
    if (idx < 5120) {                       // GtB: B-op frags, fi = nt*2+kt
        rel = idx; fi = rel >> 9; l = (rel >> 3) & 63; j = rel & 7;
        int nt = fi >> 1, kt = fi & 1;
        int c  = kt * 32 + (l >> 4) * 8 + j;     // K = x-col
        int qq = nt * 16 + (l & 15);             // N = up-col
        val = band(c, qq, fu);
    } else if (idx < 10240) {               // G2A: A-op frags, fi = mt*2+kt
        rel = idx - 5120; fi = rel >> 9; l = (rel >> 3) & 63; j = rel & 7;
        int mt = fi >> 1, kt = fi & 1;
        int pp = mt * 16 + (l & 15);             // M = up-row
        int r  = kt * 32 + (l >> 4) * 8 + j;     // K = x-row
        val = band(r, pp, fu);
    } else if (idx < 19456) {               // DA: A-op frags, fi = mt*3+kt
        rel = idx - 10240;
        int v = rel / 3072, rr = rel - v * 3072;
        fi = rr >> 9; l = (rr >> 3) & 63; j = rr & 7;
        int mt = fi / 3, kt = fi - mt * 3;
        int a  = mt * 16 + (l & 15);             // M = out-row
        int pp = kt * 32 + (l >> 4) * 8 + j;     // K = up-row
        val = dband(a, pp, v, fd);
    } else {                                 // D2B: B-op frags, fi = nt*3+kt
        rel = idx - 19456;
        int v = rel / 3072, rr = rel - v * 3072;
        fi = rr >> 9; l = (rr >> 3) & 63; j = rr & 7;
        int nt = fi / 3, kt = fi - nt * 3;
        int qq = kt * 32 + (l >> 4) * 8 + j;     // K = up-col
        int jj = nt * 16 + (l & 15);             // N = out-col
        val = dband(jj, qq, v, fd);
    }
    ws[idx] = (short)f2bf(val);
}

__global__ __launch_bounds__(256) void upfirdn_mfma(
    const float* __restrict__ xin_all,
    const float* __restrict__ bias,
    const short* __restrict__ cws,
    float* __restrict__ out)
{
    __shared__ __align__(16) short SH[17536];     // 35.1 KB -> 4 blocks/CU
    short* Xl = SH;            // 48 x 72 [r][c]    (dead after S1; T aliases)
    short* B1 = SH + 3456;     // 80 x 72 [qq][r]   (B-operand of S2)
    short* Ut = SH + 9216;     // 80 x 104 [qq][pp] (B-operand of S3)
    short* T  = SH;            // 32 x 104 [a][qq]  (A-operand of S4)

    const int tid  = threadIdx.x;
    const int lane = tid & 63, w = tid >> 6;
    const int l15  = lane & 15, q4 = lane >> 4;
    const int bx = blockIdx.x, by = blockIdx.y, bc = blockIdx.z;
    const int i0 = by * 32, j0 = bx * 32;

    const short* GtB = cws;
    const short* G2A = cws + 5120;
    const short* DA  = cws + 10240 + ((by == 0) ? 0 : (by == 3) ? 2 : 1) * 3072;
    const short* D2B = cws + 19456 + ((bx == 0) ? 0 : (bx == 3) ? 2 : 1) * 3072;

    int* Xli = (int*)Xl;
    int* B1i = (int*)B1;
    int* Uti = (int*)Ut;

    // ---- Phase 0: zero all pad regions + load X tile (crop+1, +bias) ----
    // Xl pad: int-cols 22..35 of rows 0..42, full rows 43..47 (disjoint from fill)
    for (int id = tid; id < 782; id += 256) {
        if (id < 602) { int r = id / 14, c = 22 + id % 14; Xli[r * 36 + c] = 0; }
        else { int k = id - 602; int r = 43 + k / 36, c = k % 36; Xli[r * 36 + c] = 0; }
    }
    // B1 K-pad cols 48..63 (shorts) = ints 24..31, 80 rows
    for (int id = tid; id < 640; id += 256)
        B1i[(id >> 3) * 36 + 24 + (id & 7)] = 0;
    // Ut K-pad cols 80..95 = ints 40..47, 80 rows
    for (int id = tid; id < 640; id += 256)
        Uti[(id >> 3) * 52 + 40 + (id & 7)] = 0;
    // X fill: 43 rows x 22 col-pairs
    {
        const float* xp = xin_all + (size_t)bc * (130 * 130);
        const float bv = bias[bc & 63];
        const bool interior = (bx == 1 || bx == 2) && (by == 1 || by == 2);
        for (int e = tid; e < 946; e += 256) {
            int r = e / 22, pc = e - r * 22;
            int c0 = 2 * pc;
            int gr = i0 - 5 + r, gc = j0 - 5 + c0;
            float f0, f1;
            if (interior) {
                const float* s = xp + (gr + 1) * 130 + (gc + 1);
                f0 = s[0] + bv; f1 = s[1] + bv;
            } else {
                bool rok = (unsigned)gr < 128u;
                f0 = (rok && (unsigned)gc < 128u)
                         ? xp[(gr + 1) * 130 + gc + 1] + bv : 0.f;
                f1 = (rok && (unsigned)(gc + 1) < 128u)
                         ? xp[(gr + 1) * 130 + gc + 2] + bv : 0.f;
            }
            if (c0 + 1 >= 43) f1 = 0.f;          // col 43 is K-pad
            Xli[r * 36 + pc] = f2bf(f0) | (f2bf(f1) << 16);
        }
    }
    __syncthreads();

    // ---- S1: B1 = X * Gt.  15 tiles (nt-major: consecutive share GtB frags) ----
    for (int t = (15 * w) / 4; t < (15 * (w + 1)) / 4; ++t) {
        int nt = t / 3, mt = t - nt * 3;
        v4f acc = {0.f, 0.f, 0.f, 0.f};
#pragma unroll
        for (int kt = 0; kt < 2; ++kt) {
            v8s a = *(const v8s*)&Xl[(mt * 16 + l15) * 72 + kt * 32 + q4 * 8];
            v8s b = *(const v8s*)&GtB[(nt * 2 + kt) * 512 + lane * 8];
            acc = __builtin_amdgcn_mfma_f32_16x16x32_bf16(a, b, acc, 0, 0, 0);
        }
        int qq = nt * 16 + l15, r0 = mt * 16 + q4 * 4;
        *(int2*)&B1[qq * 72 + r0] =
            make_int2(f2bf(acc[0]) | (f2bf(acc[1]) << 16),
                      f2bf(acc[2]) | (f2bf(acc[3]) << 16));
    }
    __syncthreads();

    // ---- S2: U = G2 * B1, then leaky*gain.  25 tiles (mt-major) ----
    for (int t = (25 * w) / 4; t < (25 * (w + 1)) / 4; ++t) {
        int mt = t / 5, nt = t - mt * 5;
        v4f acc = {0.f, 0.f, 0.f, 0.f};
#pragma unroll
        for (int kt = 0; kt < 2; ++kt) {
            v8s a = *(const v8s*)&G2A[(mt * 2 + kt) * 512 + lane * 8];
            v8s b = *(const v8s*)&B1[(nt * 16 + l15) * 72 + kt * 32 + q4 * 8];
            acc = __builtin_amdgcn_mfma_f32_16x16x32_bf16(a, b, acc, 0, 0, 0);
        }
#pragma unroll
        for (int i = 0; i < 4; ++i) {
            float u = acc[i];
            acc[i] = GAIN_C * u + NEG_C * fminf(u, 0.f);
        }
        int qq = nt * 16 + l15, pp0 = mt * 16 + q4 * 4;
        *(int2*)&Ut[qq * 104 + pp0] =
            make_int2(f2bf(acc[0]) | (f2bf(acc[1]) << 16),
                      f2bf(acc[2]) | (f2bf(acc[3]) << 16));
    }
    __syncthreads();

    // ---- S3: T = D * U.  10 tiles. Also zero T K-pad cols 80..95. ----
    if (tid < 256) {  // 32 rows x 8 ints (shorts 80..95): one int per thread
        int r = tid >> 3, c = tid & 7;
        ((int*)T)[r * 52 + 40 + c] = 0;
    }
    for (int t = (10 * w) / 4; t < (10 * (w + 1)) / 4; ++t) {
        int mt = t / 5, nt = t - mt * 5;
        v4f acc = {0.f, 0.f, 0.f, 0.f};
#pragma unroll
        for (int kt = 0; kt < 3; ++kt) {
            v8s a = *(const v8s*)&DA[(mt * 3 + kt) * 512 + lane * 8];
            v8s b = *(const v8s*)&Ut[(nt * 16 + l15) * 104 + kt * 32 + q4 * 8];
            acc = __builtin_amdgcn_mfma_f32_16x16x32_bf16(a, b, acc, 0, 0, 0);
        }
        int a0 = mt * 16 + q4 * 4, qq = nt * 16 + l15;
#pragma unroll
        for (int i = 0; i < 4; ++i)
            T[(a0 + i) * 104 + qq] = (short)f2bf(acc[i]);
    }
    __syncthreads();

    // ---- S4: Out = T * D2t.  4 tiles, one per wave. fp32 stores. ----
    {
        int mt = w >> 1, nt = w & 1;
        v4f acc = {0.f, 0.f, 0.f, 0.f};
#pragma unroll
        for (int kt = 0; kt < 3; ++kt) {
            v8s a = *(const v8s*)&T[(mt * 16 + l15) * 104 + kt * 32 + q4 * 8];
            v8s b = *(const v8s*)&D2B[(nt * 3 + kt) * 512 + lane * 8];
            acc = __builtin_amdgcn_mfma_f32_16x16x32_bf16(a, b, acc, 0, 0, 0);
        }
        float* op = out + (size_t)bc * 16384
                  + (size_t)(i0 + mt * 16 + q4 * 4) * 128 + (j0 + nt * 16 + l15);
#pragma unroll
        for (int i = 0; i < 4; ++i) op[i * 128] = acc[i];
    }
}

extern "C" void kernel_launch(void* const* d_in, const int* in_sizes, int n_in,
                              void* d_out, int out_size, void* d_ws, size_t ws_size,
                              hipStream_t stream) {
    const float* x  = (const float*)d_in[0];
    const float* bs = (const float*)d_in[1];
    const float* fu = (const float*)d_in[2];
    const float* fd = (const float*)d_in[3];
    float* outp = (float*)d_out;
    short* ws = (short*)d_ws;

    build_consts<<<112, 256, 0, stream>>>(fu, fd, ws);           // 28672 elems
    upfirdn_mfma<<<dim3(4, 4, 512), 256, 0, stream>>>(x, bs, ws, outp);
}

// Round 6
// 124.100 us; speedup vs baseline: 1.2275x; 1.2275x over previous
//
#include <hip/hip_runtime.h>

// Fused UpFIRDn2d via banded MFMA chain: crop(1) -> +bias -> repeat-up x2 ->
// sep 12-tap FIR -> leaky_relu(0.2)*sqrt(2) -> sep 12-tap FIR -> down x2.
// x: (8,64,130,130) f32; out: (8,64,128,128) f32.
//
// Round 6: banded-K windows (each 16-wide output tile of an up-conv reads a
// 14-wide input window -> K=32, one MFMA; down-conv tiles read 42 -> K=64).
// 68 MFMA/block (was 122). 320 threads = 5 waves; tile counts 15/25/10
// divide evenly. LDS 25.75 KB -> 6 blocks/CU (30 waves). Pads are computed
// zeros (constants zero outside band) -> no zero-fill phase.
// Stage algebra (verified round 5):
//   S1: B1[r][qq]  = sum_c  X[r][c]   * Gt[c][qq]    M48 N80 Kwin32
//   S2: U [pp][qq] = sum_r  G2[pp][r] * B1[r][qq]    M80 N80 Kwin32, then leaky
//   S3: T [a][qq]  = sum_pp D[a][pp]  * U[pp][qq]    M32 N80 Kwin64
//   S4: Out[a][j]  = sum_qq T[a][qq]  * D2t[qq][j]   M32 N32 Kwin64
// Edge clipping folded into 3 variants of D (by) and D2t (bx).

#define GAIN_C 1.4142135623730951f
#define NEG_C ((0.2f - 1.0f) * GAIN_C)

typedef short v8s __attribute__((ext_vector_type(8)));
typedef float v4f __attribute__((ext_vector_type(4)));

__device__ __forceinline__ int f2bf(float f) {   // fp32 -> bf16 bits (RNE)
    unsigned u = __float_as_uint(f);
    return (int)((u + 0x7FFFu + ((u >> 16) & 1u)) >> 16) & 0xFFFF;
}
__device__ __forceinline__ int pack_bf2(float a, float b) {
#if __has_builtin(__builtin_amdgcn_cvt_pk_bf16_f32)
    typedef __bf16 bf2 __attribute__((ext_vector_type(2)));
    bf2 r = __builtin_amdgcn_cvt_pk_bf16_f32(a, b);
    int o; __builtin_memcpy(&o, &r, 4); return o;
#else
    return f2bf(a) | (f2bf(b) << 16);
#endif
}

// band(x, q): up-conv weight linking local x index x to local up index q.
__device__ float band(int x, int q, const float* fu) {
    if (q >= 74 || x >= 43 || x < 0) return 0.f;
    int p = q >> 1, d = x - p;
    if (q & 1) {
        if (d < 0 || d > 6) return 0.f;
        if (d == 0) return fu[0];
        if (d == 6) return fu[11];
        return fu[2 * d - 1] + fu[2 * d];
    } else {
        if (d < 0 || d > 5) return 0.f;
        return fu[2 * d] + fu[2 * d + 1];
    }
}
// dband(o, q, v): down-conv weight, out index o, up index q; variant v:
// 0 = first tile (zero q<5), 2 = last tile (zero q>=69).
__device__ float dband(int o, int q, int v, const float* fd) {
    if (q >= 74 || q < 0) return 0.f;
    if (v == 0 && q < 5) return 0.f;
    if (v == 2 && q >= 69) return 0.f;
    int k = q - 2 * o;
    if (k < 0 || k > 11) return 0.f;
    return fd[k];
}

// ws layout (bf16): GtB 5x512 @0 | G2A 5x512 @2560 |
// DA 3var x (2mt x 2kt) x512 @5120 | D2B 3var x (2nt x 2kt) x512 @11264.
// Total 17408 shorts. K-window starts: S1/S2 k0 = min(8*t,16);
// S3/S4 k0 = t ? 16 : 0.  (Keep in sync with consumer kernel!)
__global__ __launch_bounds__(256) void build_consts(
    const float* __restrict__ fu, const float* __restrict__ fd,
    short* __restrict__ ws)
{
    int idx = blockIdx.x * 256 + threadIdx.x;   // grid covers 17408 exactly
    int l = (idx >> 3) & 63, j = idx & 7;
    int l15 = l & 15, kq = (l >> 4) * 8 + j;
    float val;
    if (idx < 2560) {                         // GtB: B-op, frag = nt
        int nt = idx >> 9;
        int k0 = 8 * nt < 16 ? 8 * nt : 16;
        val = band(k0 + kq, 16 * nt + l15, fu);
    } else if (idx < 5120) {                  // G2A: A-op, frag = mt
        int mt = (idx - 2560) >> 9;
        int k0 = 8 * mt < 16 ? 8 * mt : 16;
        val = band(k0 + kq, 16 * mt + l15, fu);
    } else if (idx < 11264) {                 // DA: A-op, frag = (v, mt*2+kt)
        int rel = idx - 5120;
        int v = rel >> 11, fi = (rel & 2047) >> 9;
        int mt = fi >> 1, kt = fi & 1;
        int pp = (mt ? 16 : 0) + 32 * kt + kq;
        val = dband(16 * mt + l15, pp, v, fd);
    } else {                                  // D2B: B-op, frag = (v, nt*2+kt)
        int rel = idx - 11264;
        int v = rel >> 11, fi = (rel & 2047) >> 9;
        int nt = fi >> 1, kt = fi & 1;
        int qq = (nt ? 16 : 0) + 32 * kt + kq;
        val = dband(16 * nt + l15, qq, v, fd);
    }
    ws[idx] = (short)f2bf(val);
}

#define XPITCH 48   // X [48 rows][48] bf16
#define BPITCH 48   // B1t [80 qq][48 r]
#define UPITCH 88   // Ut [80 qq][88 pp]; 176 B rows: 2-way bank step (free)
#define TPITCH 80   // T [32 a][80 qq], aliases X/B1t region

__global__ __launch_bounds__(320, 8) void upfirdn_mfma(
    const float* __restrict__ xin_all,
    const float* __restrict__ bias,
    const short* __restrict__ cws,
    float* __restrict__ out)
{
    __shared__ __align__(16) short SH[2304 + 3840 + 7040];  // 25.75 KB
    short* Xl  = SH;            // 48x48  (dead after S1; T aliases)
    short* B1t = SH + 2304;     // 80x48  [qq][r]
    short* Ut  = SH + 6144;     // 80x88  [qq][pp]
    short* T   = SH;            // 32x80  [a][qq]

    const int tid  = threadIdx.x;
    const int lane = tid & 63, w = tid >> 6;
    const int l15  = lane & 15, q4 = lane >> 4;
    const int bx = blockIdx.x, by = blockIdx.y, bc = blockIdx.z;
    const int i0 = by * 32, j0 = bx * 32;

    const short* GtB = cws;
    const short* G2A = cws + 2560;
    const short* DA  = cws + 5120  + ((by == 0) ? 0 : (by == 3) ? 2 : 1) * 2048;
    const short* D2B = cws + 11264 + ((bx == 0) ? 0 : (bx == 3) ? 2 : 1) * 2048;

    // ---- Phase 0: load X tile (crop +1, +bias), pads zero. 48x24 int items. ----
    {
        const float* xp = xin_all + (size_t)bc * (130 * 130);
        const float bv = bias[bc & 63];
        const bool colInt = (bx == 1) | (bx == 2);
        int* Xli = (int*)Xl;
        for (int idx = tid; idx < 1152; idx += 320) {
            int r = idx / 24, cp = idx - r * 24;
            int gr = i0 - 5 + r;
            float f0 = 0.f, f1 = 0.f;
            if (r < 43 && (unsigned)gr < 128u && cp < 22) {
                const float* rowp = xp + (gr + 1) * 130 + 1;
                int gc0 = j0 - 5 + 2 * cp;
                if (colInt) {
                    f0 = rowp[gc0] + bv;
                    if (cp < 21) f1 = rowp[gc0 + 1] + bv;
                } else {
                    if ((unsigned)gc0 < 128u) f0 = rowp[gc0] + bv;
                    if (cp < 21 && (unsigned)(gc0 + 1) < 128u)
                        f1 = rowp[gc0 + 1] + bv;
                }
            }
            Xli[r * 24 + cp] = pack_bf2(f0, f1);
        }
    }
    __syncthreads();

    // ---- S1: B1 = X * Gt.  wave w -> nt = w; mt 0..2. K-window min(8nt,16). ----
    {
        const int nt = w;
        const int k0 = 8 * nt < 16 ? 8 * nt : 16;
        v8s bf = *(const v8s*)&GtB[nt * 512 + lane * 8];
#pragma unroll
        for (int mt = 0; mt < 3; ++mt) {
            v8s a = *(const v8s*)&Xl[(16 * mt + l15) * XPITCH + k0 + q4 * 8];
            v4f acc = {0.f, 0.f, 0.f, 0.f};
            acc = __builtin_amdgcn_mfma_f32_16x16x32_bf16(a, bf, acc, 0, 0, 0);
            // C: col = qq = 16nt+l15, rows r = 16mt + q4*4 + i
            *(int2*)&B1t[(16 * nt + l15) * BPITCH + 16 * mt + q4 * 4] =
                make_int2(pack_bf2(acc[0], acc[1]), pack_bf2(acc[2], acc[3]));
        }
    }
    __syncthreads();

    // ---- S2: U = leaky(G2 * B1).  wave w -> mt = w; nt 0..4. One A-frag/wave. ----
    {
        const int mt = w;
        const int k0 = 8 * mt < 16 ? 8 * mt : 16;
        v8s af = *(const v8s*)&G2A[mt * 512 + lane * 8];
#pragma unroll
        for (int nt = 0; nt < 5; ++nt) {
            v8s b = *(const v8s*)&B1t[(16 * nt + l15) * BPITCH + k0 + q4 * 8];
            v4f acc = {0.f, 0.f, 0.f, 0.f};
            acc = __builtin_amdgcn_mfma_f32_16x16x32_bf16(af, b, acc, 0, 0, 0);
#pragma unroll
            for (int i = 0; i < 4; ++i)
                acc[i] = GAIN_C * acc[i] + NEG_C * fminf(acc[i], 0.f);
            // C: col = qq = 16nt+l15, rows pp = 16mt + q4*4 + i
            *(int2*)&Ut[(16 * nt + l15) * UPITCH + 16 * mt + q4 * 4] =
                make_int2(pack_bf2(acc[0], acc[1]), pack_bf2(acc[2], acc[3]));
        }
    }
    __syncthreads();

    // ---- S3: T = D * U.  wave w -> nt = w; mt 0..1, K-window 64 @ (mt?16:0). ----
    {
        const int nt = w;
#pragma unroll
        for (int mt = 0; mt < 2; ++mt) {
            const int k0 = mt ? 16 : 0;
            v4f acc = {0.f, 0.f, 0.f, 0.f};
#pragma unroll
            for (int kt = 0; kt < 2; ++kt) {
                v8s a = *(const v8s*)&DA[(mt * 2 + kt) * 512 + lane * 8];
                v8s b = *(const v8s*)&Ut[(16 * nt + l15) * UPITCH
                                         + k0 + 32 * kt + q4 * 8];
                acc = __builtin_amdgcn_mfma_f32_16x16x32_bf16(a, b, acc, 0, 0, 0);
            }
            // C: col = qq = 16nt+l15, rows a = 16mt + q4*4 + i  (b16 scatter)
#pragma unroll
            for (int i = 0; i < 4; ++i)
                T[(16 * mt + q4 * 4 + i) * TPITCH + 16 * nt + l15] =
                    (short)f2bf(acc[i]);
        }
    }
    __syncthreads();

    // ---- S4: Out = T * D2t.  waves 0..3: (mt = w>>1, nt = w&1). ----
    if (w < 4) {
        const int mt = w >> 1, nt = w & 1;
        const int k0 = nt ? 16 : 0;
        v4f acc = {0.f, 0.f, 0.f, 0.f};
#pragma unroll
        for (int kt = 0; kt < 2; ++kt) {
            v8s a = *(const v8s*)&T[(16 * mt + l15) * TPITCH + k0 + 32 * kt + q4 * 8];
            v8s b = *(const v8s*)&D2B[(nt * 2 + kt) * 512 + lane * 8];
            acc = __builtin_amdgcn_mfma_f32_16x16x32_bf16(a, b, acc, 0, 0, 0);
        }
        float* op = out + (size_t)bc * 16384
                  + (size_t)(i0 + 16 * mt + q4 * 4) * 128 + (j0 + 16 * nt + l15);
#pragma unroll
        for (int i = 0; i < 4; ++i) op[i * 128] = acc[i];
    }
}

extern "C" void kernel_launch(void* const* d_in, const int* in_sizes, int n_in,
                              void* d_out, int out_size, void* d_ws, size_t ws_size,
                              hipStream_t stream) {
    const float* x  = (const float*)d_in[0];
    const float* bs = (const float*)d_in[1];
    const float* fu = (const float*)d_in[2];
    const float* fd = (const float*)d_in[3];
    float* outp = (float*)d_out;
    short* ws = (short*)d_ws;

    build_consts<<<68, 256, 0, stream>>>(fu, fd, ws);    // 17408 elems
    upfirdn_mfma<<<dim3(4, 4, 512), 320, 0, stream>>>(x, bs, ws, outp);
}